// Round 4
// baseline (757.790 us; speedup 1.0000x reference)
//
#include <hip/hip_runtime.h>

// GNN_Sine fused, MFMA edition — v4 (resubmit: round-3 failure was container
// infra, kernel never ran).
// B=65536, NJ=24, dims 13->64->64->64->65, fp32 in/out.
//
// Changes vs v3 (455 us, occ 34%, VALU 36.5%, FETCH 122 MB):
//  * aw matrices staged to LDS at block start (9.2 KB): the 70 per-edge
//    uniform aw reads in agg were SMEM s_loads interleaved with H ds_reads.
//    SMEM+DS share lgkmcnt but complete out-of-order across units, forcing
//    full lgkmcnt(0) drains -> occupancy-proof serialization (the v3 lesson:
//    +50% occupancy bought 0%). All-DS lgkm traffic is in-order -> the
//    compiler can emit fine-grained lgkmcnt(N).
//  * pack2 = round-half-up (+0x8000, take hi16): 5 VALU ops vs 12-op manual
//    RNE. Max error identical (0.5 ulp; only exact ties differ). ~26% of all
//    VALU instructions were RNE packing.
//  * feat64 tail back to v1's separate epilogue (v3's interleaved tail store
//    doubled FETCH: partial-line dword stores between x4 bursts made
//    write-allocate worse, not better).
//  * LDS 59 KB -> 2 blocks/CU (proven cost-free in v3's occupancy A/B).

#define NJ 24
#define TB 16

typedef __attribute__((ext_vector_type(8))) short bf16x8;
typedef __attribute__((ext_vector_type(4))) float f32x4;

__device__ constexpr int NBR_OFF_C[NJ + 1] = {0,4,7,10,13,16,19,22,25,28,33,35,37,40,43,46,48,51,54,57,60,63,66,68,70};
__device__ constexpr int NBR_LIST_C[70] = {
    0,1,2,3,  0,1,4,  0,2,5,  0,3,6,  1,4,7,  2,5,8,  3,6,9,  4,7,10,
    5,8,11,  6,9,12,13,14,  7,10,  8,11,  9,12,15,  9,13,16,  9,14,17,
    12,15,  13,16,18,  14,17,19,  16,18,20,  17,19,21,  18,20,22,  19,21,23,
    20,22,  21,23
};

__device__ __forceinline__ float bf2f(unsigned short u) {
    return __uint_as_float(((unsigned int)u) << 16);
}
__device__ __forceinline__ unsigned short f2bf(float f) {   // exact RNE (prepack only)
    unsigned int u = __float_as_uint(f);
    u += 0x7fffu + ((u >> 16) & 1u);
    return (unsigned short)(u >> 16);
}
// round-half-up bf16 pack: same 0.5-ulp max error as RNE, 5 VALU ops.
__device__ __forceinline__ unsigned short f2bf_fast(float f) {
    return (unsigned short)((__float_as_uint(f) + 0x8000u) >> 16);
}
__device__ __forceinline__ unsigned int pack2(float a, float b) {
    const unsigned int ua = __float_as_uint(a) + 0x8000u;
    const unsigned int ub = __float_as_uint(b) + 0x8000u;
    return (ua >> 16) | (ub & 0xffff0000u);
}

// ---------------- weight prepack: fp32 [joint][l][jout] -> bf16 A-fragments ----
// Frag layout: elem = frag*512 + lane*8 + j ; lane holds A[m=lane&15][k=(lane>>4)*8+j]
//   m = jout within Mtile, k = l within ktile (K=32).
// Frag index map: L0 (96): (joint*4+mt)         kt=0   base 0
//                 L1 (192): joint*8+mt*2+kt            base 96
//                 L2 (192):                            base 288
//                 L3 (240): joint*10+mt*2+kt (MT=5)    base 480
__global__ __launch_bounds__(256) void prepack(
    const float* __restrict__ w0, const float* __restrict__ w1,
    const float* __restrict__ w2, const float* __restrict__ w3,
    unsigned short* __restrict__ wp)
{
    const int f = blockIdx.x;
    const int t = threadIdx.x;
    const int lane = t >> 2;
    const int jp = t & 3;

    const float* w; int DIN, DOUT, joint, mt, kt;
    if (f < 96)       { w = w0; DIN = 13; DOUT = 64; int g = f;       joint = g >> 2; mt = g & 3;        kt = 0;     }
    else if (f < 288) { w = w1; DIN = 64; DOUT = 64; int g = f - 96;  joint = g >> 3; mt = (g >> 1) & 3; kt = g & 1; }
    else if (f < 480) { w = w2; DIN = 64; DOUT = 64; int g = f - 288; joint = g >> 3; mt = (g >> 1) & 3; kt = g & 1; }
    else              { w = w3; DIN = 64; DOUT = 65; int g = f - 480; joint = g / 10; int r = g % 10; mt = r >> 1; kt = r & 1; }

    const int jout = mt * 16 + (lane & 15);
    unsigned int packed = 0;
#pragma unroll
    for (int jj = 0; jj < 2; ++jj) {
        const int j = jp * 2 + jj;
        const int l = kt * 32 + (lane >> 4) * 8 + j;
        float v = 0.f;
        if (l < DIN && jout < DOUT) v = w[(joint * DIN + l) * DOUT + jout];
        packed |= (unsigned int)f2bf(v) << (16 * jj);
    }
    *(unsigned int*)(wp + (size_t)f * 512 + lane * 8 + jp * 2) = packed;
}

// ---------------- phase 1: per-joint linear via MFMA --------------------------
// In-place on buf: wave wv owns joints k = wv*6 .. wv*6+5 exclusively, and the
// per-lane ds_reads all precede the ds_writes in program order (wave-lockstep).
template<int KT, int MT>
__device__ __forceinline__ void linear_phase(unsigned short* buf, unsigned short* abuf,
    const unsigned short* __restrict__ wf, int wv, int lane)
{
    const int bl = lane & 15;       // b (N col)
    const int quad = lane >> 4;
    const int sx = (bl & 7) << 3;   // row&7 == bl&7 : lane-constant swizzle
    for (int jj = 0; jj < 6; ++jj) {
        const int k = wv * 6 + jj;
        const int rbase = (k * TB + bl) * 64;
        // B-op: activation fragments (K-contiguous ds_read_b128, swizzled row)
        bf16x8 bfr[KT];
#pragma unroll
        for (int kt = 0; kt < KT; ++kt)
            bfr[kt] = *(bf16x8*)&buf[rbase + ((kt * 32 + quad * 8) ^ sx)];
        // A-op: prepacked weight fragments (coalesced global dwordx4)
        const unsigned short* wj = wf + (size_t)k * (MT * KT * 512) + lane * 8;
        bf16x8 afr[MT][KT];
#pragma unroll
        for (int mt = 0; mt < MT; ++mt)
#pragma unroll
            for (int kt = 0; kt < KT; ++kt)
                afr[mt][kt] = *(const bf16x8*)(wj + (mt * KT + kt) * 512);
        f32x4 acc[MT];
#pragma unroll
        for (int mt = 0; mt < MT; ++mt) {
            acc[mt] = (f32x4){0.f, 0.f, 0.f, 0.f};
#pragma unroll
            for (int kt = 0; kt < KT; ++kt)
                acc[mt] = __builtin_amdgcn_mfma_f32_16x16x32_bf16(afr[mt][kt], bfr[kt], acc[mt], 0, 0, 0);
        }
        // H store: lane holds rows jout = mt*16 + quad*4 .. +3 at col b=bl
        //  -> packed ds_write_b64 back into the same swizzled layout.
        // MT==5: only jout 64 is real -> feat64 sidecar (abuf), quad0 only.
#pragma unroll
        for (int mt = 0; mt < MT; ++mt) {
            if (mt < 4) {
                uint2 p;
                p.x = pack2(acc[mt].x, acc[mt].y);
                p.y = pack2(acc[mt].z, acc[mt].w);
                *(uint2*)&buf[rbase + ((mt * 16 + quad * 4) ^ sx)] = p;
            } else if (quad == 0) {
                abuf[k * TB + bl] = f2bf_fast(acc[mt].x);
            }
        }
    }
}

// ---------------- phase 2: sparse tree aggregation (VALU) ---------------------
// awl points into LDS (staged at block start): all lgkm traffic in this phase
// is DS-only -> in-order -> fine-grained s_waitcnt, no full drains.
template<bool LAST>
__device__ __forceinline__ void agg_phase(unsigned short* buf,
    const unsigned short* abuf, const float* awl,
    const float* __restrict__ bias,
    float* __restrict__ out, int base, int wv, int lane)
{
    const int bsub = lane >> 4;            // 0..3
    const int jq = lane & 15;              // feat quad (4 feats)
    const int b = wv * 4 + bsub;           // 0..15
    const int eo = (jq * 4) ^ ((b & 7) << 3);   // swizzled, lane-constant

    float acc[NJ][4];
#pragma unroll
    for (int n = 0; n < NJ; ++n) {
        acc[n][0] = 0.f; acc[n][1] = 0.f; acc[n][2] = 0.f; acc[n][3] = 0.f;
    }
    const float4 bv = *(const float4*)(bias + jq * 4);

    // read each H row once, scatter-add into compile-time-indexed accumulators
#pragma unroll
    for (int m = 0; m < NJ; ++m) {
        uint2 raw = *(uint2*)&buf[(m * TB + b) * 64 + eo];
        const float h0 = __uint_as_float(raw.x << 16);
        const float h1 = __uint_as_float(raw.x & 0xffff0000u);
        const float h2 = __uint_as_float(raw.y << 16);
        const float h3 = __uint_as_float(raw.y & 0xffff0000u);
#pragma unroll
        for (int e = NBR_OFF_C[m]; e < NBR_OFF_C[m + 1]; ++e) {
            const int n = NBR_LIST_C[e];
            const float c = awl[n * NJ + m];   // LDS broadcast read
            acc[n][0] += c * h0; acc[n][1] += c * h1;
            acc[n][2] += c * h2; acc[n][3] += c * h3;
        }
    }

    if (!LAST) {
#pragma unroll
        for (int n = 0; n < NJ; ++n) {
            const float v0 = fmaxf(acc[n][0] + bv.x, 0.f);
            const float v1 = fmaxf(acc[n][1] + bv.y, 0.f);
            const float v2 = fmaxf(acc[n][2] + bv.z, 0.f);
            const float v3 = fmaxf(acc[n][3] + bv.w, 0.f);
            uint2 p; p.x = pack2(v0, v1); p.y = pack2(v2, v3);
            *(uint2*)&buf[(n * TB + b) * 64 + eo] = p;
        }
    } else {
        float* ob = out + (size_t)(base + b) * (NJ * 65);
#pragma unroll
        for (int n = 0; n < NJ; ++n) {
            float* p = ob + n * 65 + jq * 4;
            p[0] = acc[n][0] + bv.x;
            p[1] = acc[n][1] + bv.y;
            p[2] = acc[n][2] + bv.z;
            p[3] = acc[n][3] + bv.w;
        }
        // feature 64 epilogue: lanes 0..23 own one output joint each (v1 style)
        if (lane < NJ) {
            const int n = lane;
            const float b64v = bias[64];
            float a64[4] = {0.f, 0.f, 0.f, 0.f};
            for (int e = NBR_OFF_C[n]; e < NBR_OFF_C[n + 1]; ++e) {
                const int m = NBR_LIST_C[e];
                const float c = awl[n * NJ + m];
#pragma unroll
                for (int bb = 0; bb < 4; ++bb)
                    a64[bb] += c * bf2f(abuf[m * TB + wv * 4 + bb]);
            }
#pragma unroll
            for (int bb = 0; bb < 4; ++bb)
                out[(size_t)(base + wv * 4 + bb) * (NJ * 65) + n * 65 + 64] = a64[bb] + b64v;
        }
    }
}

// ---------------- main fused kernel -------------------------------------------
__global__ __launch_bounds__(256, 2) void gnn_mfma(
    const float* __restrict__ x, const unsigned short* __restrict__ wp,
    const float* __restrict__ aw0, const float* __restrict__ b0,
    const float* __restrict__ aw1, const float* __restrict__ b1,
    const float* __restrict__ aw2, const float* __restrict__ b2,
    const float* __restrict__ aw3, const float* __restrict__ b3,
    float* __restrict__ out)
{
    __shared__ __align__(16) unsigned short buf[NJ * TB * 64];  // 49,152 B
    __shared__ __align__(8)  unsigned short abuf[NJ * TB];      //    768 B (L3 feat64)
    __shared__ __align__(16) float awl[4 * NJ * NJ];            //  9,216 B (aw in LDS)

    const int t = threadIdx.x;
    const int lane = t & 63;
    const int wv = t >> 6;
    const int base = blockIdx.x * TB;

    // stage all 4 adjacency-weight matrices into LDS (coalesced, overlaps x-load)
    for (int i = t; i < NJ * NJ; i += 256) {
        awl[i]                = aw0[i];
        awl[NJ * NJ + i]      = aw1[i];
        awl[2 * NJ * NJ + i]  = aw2[i];
        awl[3 * NJ * NJ + i]  = aw3[i];
    }

    // load x tile -> swizzled [joint][b][feat] bf16, feats 13..31 zeroed (K=32
    // pad), joint 0 masked to zero (mask_root).
    for (int i = t; i < NJ * TB * 16; i += 256) {
        const int k = i >> 8;            // /(16 pairs * 16 b)
        const int b = (i >> 4) & 15;
        const int f2 = (i & 15) * 2;
        float v0 = 0.f, v1 = 0.f;
        if (k > 0) {
            const float* xr = x + (size_t)(base + b) * 312 + k * 13;
            if (f2 < 13)     v0 = xr[f2];
            if (f2 + 1 < 13) v1 = xr[f2 + 1];
        }
        const int row = k * TB + b;
        *(unsigned int*)&buf[row * 64 + (f2 ^ ((row & 7) << 3))] = pack2(v0, v1);
    }
    __syncthreads();

    linear_phase<1, 4>(buf, abuf, wp, wv, lane);                 // L0: K=32(13+pad)
    __syncthreads();
    agg_phase<false>(buf, abuf, awl, b0, nullptr, base, wv, lane);
    __syncthreads();
    linear_phase<2, 4>(buf, abuf, wp + 96 * 512, wv, lane);      // L1
    __syncthreads();
    agg_phase<false>(buf, abuf, awl + NJ * NJ, b1, nullptr, base, wv, lane);
    __syncthreads();
    linear_phase<2, 4>(buf, abuf, wp + 288 * 512, wv, lane);     // L2
    __syncthreads();
    agg_phase<false>(buf, abuf, awl + 2 * NJ * NJ, b2, nullptr, base, wv, lane);
    __syncthreads();
    linear_phase<2, 5>(buf, abuf, wp + 480 * 512, wv, lane);     // L3: MT=5 (65 cols)
    __syncthreads();
    agg_phase<true>(buf, abuf, awl + 3 * NJ * NJ, b3, out, base, wv, lane);
}

extern "C" void kernel_launch(void* const* d_in, const int* in_sizes, int n_in,
                              void* d_out, int out_size, void* d_ws, size_t ws_size,
                              hipStream_t stream)
{
    const float* x   = (const float*)d_in[0];
    const float* w0  = (const float*)d_in[1];
    const float* aw0 = (const float*)d_in[2];
    const float* b0  = (const float*)d_in[3];
    const float* w1  = (const float*)d_in[4];
    const float* aw1 = (const float*)d_in[5];
    const float* b1  = (const float*)d_in[6];
    const float* w2  = (const float*)d_in[7];
    const float* aw2 = (const float*)d_in[8];
    const float* b2  = (const float*)d_in[9];
    const float* w3  = (const float*)d_in[10];
    const float* aw3 = (const float*)d_in[11];
    const float* b3  = (const float*)d_in[12];
    float* out = (float*)d_out;
    unsigned short* wp = (unsigned short*)d_ws;   // needs 737,280 B (720 frags * 1 KB)

    prepack<<<720, 256, 0, stream>>>(w0, w1, w2, w3, wp);

    const int blocks = 65536 / TB;   // 4096
    gnn_mfma<<<blocks, 256, 0, stream>>>(x, wp, aw0, b0, aw1, b1,
                                         aw2, b2, aw3, b3, out);
}

// Round 5
// 720.702 us; speedup vs baseline: 1.0515x; 1.0515x over previous
//
#include <hip/hip_runtime.h>

// GNN_Sine fused, MFMA edition — v5: latency-chain attack on agg.
// B=65536, NJ=24, dims 13->64->64->64->65, fp32 in/out.
//
// Evidence through v4: dur invariant (437-457 us) across occupancy 23<->34%,
// VALU -15%, FETCH 58<->122 MB => per-wave latency chain, occupancy-proof.
// Biggest phase = agg: 24 ds_read_b64 + 70 ds_read_b32(aw) interleaved with
// 280 chained FMAs into acc[24][4]; at 124 VGPR the compiler batches reads
// with ~120cy LDS latency exposed per batch (~2K cy/agg x4 layers).
//
// v5 changes:
//  * agg: prefetch ALL 24 H rows (one pipelined ds_read burst), unpack once
//    to h[24][4] regs, then gather-order per-n FMAs with ZERO memory operands.
//    acc is 4 regs per n (was 96 live), stores spread per-n. ~150 VGPR peak.
//  * aw coefficients via v_readlane: 70 edge weights/layer loaded once per
//    wave into 2 VGPRs (EDGE_IDX lane gather); per-edge c = readlane(reg,e)
//    -> SGPR operand. Removes 280 ds_read_b32/thread + lgkm entanglement.
//  * v4's awl LDS staging dropped (superseded); LDS 49,920 B.

#define NJ 24
#define TB 16

typedef __attribute__((ext_vector_type(8))) short bf16x8;
typedef __attribute__((ext_vector_type(4))) float f32x4;

__device__ constexpr int NBR_OFF_C[NJ + 1] = {0,4,7,10,13,16,19,22,25,28,33,35,37,40,43,46,48,51,54,57,60,63,66,68,70};
__device__ constexpr int NBR_LIST_C[70] = {
    0,1,2,3,  0,1,4,  0,2,5,  0,3,6,  1,4,7,  2,5,8,  3,6,9,  4,7,10,
    5,8,11,  6,9,12,13,14,  7,10,  8,11,  9,12,15,  9,13,16,  9,14,17,
    12,15,  13,16,18,  14,17,19,  16,18,20,  17,19,21,  18,20,22,  19,21,23,
    20,22,  21,23
};
// EDGE_IDX[e] = n(e)*24 + m(e) for the gather-order edge list above.
__device__ constexpr int EDGE_IDX[70] = {
    0,1,2,3,  24,25,28,  48,50,53,  72,75,78,  97,100,103,  122,125,128,
    147,150,153,  172,175,178,  197,200,203,  222,225,228,229,230,
    247,250,  272,275,  297,300,303,  321,325,328,  345,350,353,
    372,375,  397,400,402,  422,425,427,  448,450,452,  473,475,477,
    498,500,502,  523,525,527,  548,550,  573,575
};

__device__ __forceinline__ float bf2f(unsigned short u) {
    return __uint_as_float(((unsigned int)u) << 16);
}
__device__ __forceinline__ unsigned short f2bf(float f) {   // exact RNE (prepack only)
    unsigned int u = __float_as_uint(f);
    u += 0x7fffu + ((u >> 16) & 1u);
    return (unsigned short)(u >> 16);
}
// round-half-up bf16 pack: same 0.5-ulp max error as RNE, 5 VALU ops.
__device__ __forceinline__ unsigned short f2bf_fast(float f) {
    return (unsigned short)((__float_as_uint(f) + 0x8000u) >> 16);
}
__device__ __forceinline__ unsigned int pack2(float a, float b) {
    const unsigned int ua = __float_as_uint(a) + 0x8000u;
    const unsigned int ub = __float_as_uint(b) + 0x8000u;
    return (ua >> 16) | (ub & 0xffff0000u);
}

// ---------------- weight prepack: fp32 [joint][l][jout] -> bf16 A-fragments ----
// Frag layout: elem = frag*512 + lane*8 + j ; lane holds A[m=lane&15][k=(lane>>4)*8+j]
//   m = jout within Mtile, k = l within ktile (K=32).
// Frag index map: L0 (96): (joint*4+mt)         kt=0   base 0
//                 L1 (192): joint*8+mt*2+kt            base 96
//                 L2 (192):                            base 288
//                 L3 (240): joint*10+mt*2+kt (MT=5)    base 480
__global__ __launch_bounds__(256) void prepack(
    const float* __restrict__ w0, const float* __restrict__ w1,
    const float* __restrict__ w2, const float* __restrict__ w3,
    unsigned short* __restrict__ wp)
{
    const int f = blockIdx.x;
    const int t = threadIdx.x;
    const int lane = t >> 2;
    const int jp = t & 3;

    const float* w; int DIN, DOUT, joint, mt, kt;
    if (f < 96)       { w = w0; DIN = 13; DOUT = 64; int g = f;       joint = g >> 2; mt = g & 3;        kt = 0;     }
    else if (f < 288) { w = w1; DIN = 64; DOUT = 64; int g = f - 96;  joint = g >> 3; mt = (g >> 1) & 3; kt = g & 1; }
    else if (f < 480) { w = w2; DIN = 64; DOUT = 64; int g = f - 288; joint = g >> 3; mt = (g >> 1) & 3; kt = g & 1; }
    else              { w = w3; DIN = 64; DOUT = 65; int g = f - 480; joint = g / 10; int r = g % 10; mt = r >> 1; kt = r & 1; }

    const int jout = mt * 16 + (lane & 15);
    unsigned int packed = 0;
#pragma unroll
    for (int jj = 0; jj < 2; ++jj) {
        const int j = jp * 2 + jj;
        const int l = kt * 32 + (lane >> 4) * 8 + j;
        float v = 0.f;
        if (l < DIN && jout < DOUT) v = w[(joint * DIN + l) * DOUT + jout];
        packed |= (unsigned int)f2bf(v) << (16 * jj);
    }
    *(unsigned int*)(wp + (size_t)f * 512 + lane * 8 + jp * 2) = packed;
}

// ---------------- phase 1: per-joint linear via MFMA --------------------------
// In-place on buf: wave wv owns joints k = wv*6 .. wv*6+5 exclusively, and the
// per-lane ds_reads all precede the ds_writes in program order (wave-lockstep).
template<int KT, int MT>
__device__ __forceinline__ void linear_phase(unsigned short* buf, unsigned short* abuf,
    const unsigned short* __restrict__ wf, int wv, int lane)
{
    const int bl = lane & 15;       // b (N col)
    const int quad = lane >> 4;
    const int sx = (bl & 7) << 3;   // row&7 == bl&7 : lane-constant swizzle
    for (int jj = 0; jj < 6; ++jj) {
        const int k = wv * 6 + jj;
        const int rbase = (k * TB + bl) * 64;
        // B-op: activation fragments (K-contiguous ds_read_b128, swizzled row)
        bf16x8 bfr[KT];
#pragma unroll
        for (int kt = 0; kt < KT; ++kt)
            bfr[kt] = *(bf16x8*)&buf[rbase + ((kt * 32 + quad * 8) ^ sx)];
        // A-op: prepacked weight fragments (coalesced global dwordx4)
        const unsigned short* wj = wf + (size_t)k * (MT * KT * 512) + lane * 8;
        bf16x8 afr[MT][KT];
#pragma unroll
        for (int mt = 0; mt < MT; ++mt)
#pragma unroll
            for (int kt = 0; kt < KT; ++kt)
                afr[mt][kt] = *(const bf16x8*)(wj + (mt * KT + kt) * 512);
        f32x4 acc[MT];
#pragma unroll
        for (int mt = 0; mt < MT; ++mt) {
            acc[mt] = (f32x4){0.f, 0.f, 0.f, 0.f};
#pragma unroll
            for (int kt = 0; kt < KT; ++kt)
                acc[mt] = __builtin_amdgcn_mfma_f32_16x16x32_bf16(afr[mt][kt], bfr[kt], acc[mt], 0, 0, 0);
        }
        // H store: lane holds rows jout = mt*16 + quad*4 .. +3 at col b=bl
        //  -> packed ds_write_b64 back into the same swizzled layout.
        // MT==5: only jout 64 is real -> feat64 sidecar (abuf), quad0 only.
#pragma unroll
        for (int mt = 0; mt < MT; ++mt) {
            if (mt < 4) {
                uint2 p;
                p.x = pack2(acc[mt].x, acc[mt].y);
                p.y = pack2(acc[mt].z, acc[mt].w);
                *(uint2*)&buf[rbase + ((mt * 16 + quad * 4) ^ sx)] = p;
            } else if (quad == 0) {
                abuf[k * TB + bl] = f2bf_fast(acc[mt].x);
            }
        }
    }
}

// ---------------- phase 2: sparse tree aggregation (VALU) ---------------------
// eA/eB: wave-resident edge-coefficient regs for this layer (lane e of eA holds
// aw[EDGE_IDX[e]], eB holds edges 64..69 in lanes 0..5). Per-edge coefficient
// comes from v_readlane -> SGPR, so the FMA block has ZERO memory operands.
template<bool LAST>
__device__ __forceinline__ void agg_phase(unsigned short* buf,
    const unsigned short* abuf,
    unsigned int eA, unsigned int eB,
    const float* __restrict__ aw_epi,      // only used when LAST (feat64 tail)
    const float* __restrict__ bias,
    float* __restrict__ out, int base, int wv, int lane)
{
    const int bsub = lane >> 4;            // 0..3
    const int jq = lane & 15;              // feat quad (4 feats)
    const int b = wv * 4 + bsub;           // 0..15
    const int eo = (jq * 4) ^ ((b & 7) << 3);   // swizzled, lane-constant

    // prefetch ALL H rows: 24 independent ds_read_b64, one pipelined burst
    uint2 raw[NJ];
#pragma unroll
    for (int m = 0; m < NJ; ++m)
        raw[m] = *(uint2*)&buf[(m * TB + b) * 64 + eo];
    // unpack once; h[][] is fully statically indexed -> registers
    float h[NJ][4];
#pragma unroll
    for (int m = 0; m < NJ; ++m) {
        h[m][0] = __uint_as_float(raw[m].x << 16);
        h[m][1] = __uint_as_float(raw[m].x & 0xffff0000u);
        h[m][2] = __uint_as_float(raw[m].y << 16);
        h[m][3] = __uint_as_float(raw[m].y & 0xffff0000u);
    }
    const float4 bv = *(const float4*)(bias + jq * 4);

    // gather per output joint n: pure-register FMAs, store immediately
#pragma unroll
    for (int n = 0; n < NJ; ++n) {
        float a0 = 0.f, a1 = 0.f, a2 = 0.f, a3 = 0.f;
#pragma unroll
        for (int e = NBR_OFF_C[n]; e < NBR_OFF_C[n + 1]; ++e) {
            const int m = NBR_LIST_C[e];
            const float c = __uint_as_float((unsigned int)
                __builtin_amdgcn_readlane((int)(e < 64 ? eA : eB), e & 63));
            a0 += c * h[m][0]; a1 += c * h[m][1];
            a2 += c * h[m][2]; a3 += c * h[m][3];
        }
        if (!LAST) {
            const float v0 = fmaxf(a0 + bv.x, 0.f);
            const float v1 = fmaxf(a1 + bv.y, 0.f);
            const float v2 = fmaxf(a2 + bv.z, 0.f);
            const float v3 = fmaxf(a3 + bv.w, 0.f);
            uint2 p; p.x = pack2(v0, v1); p.y = pack2(v2, v3);
            *(uint2*)&buf[(n * TB + b) * 64 + eo] = p;
        } else {
            float* p = out + (size_t)(base + b) * (NJ * 65) + n * 65 + jq * 4;
            p[0] = a0 + bv.x;
            p[1] = a1 + bv.y;
            p[2] = a2 + bv.z;
            p[3] = a3 + bv.w;
        }
    }

    if (LAST) {
        // feature 64 epilogue: lanes 0..23 own one output joint each (v1 style)
        if (lane < NJ) {
            const int n = lane;
            const float b64v = bias[64];
            float a64[4] = {0.f, 0.f, 0.f, 0.f};
            for (int e = NBR_OFF_C[n]; e < NBR_OFF_C[n + 1]; ++e) {
                const int m = NBR_LIST_C[e];
                const float c = aw_epi[n * NJ + m];
#pragma unroll
                for (int bb = 0; bb < 4; ++bb)
                    a64[bb] += c * bf2f(abuf[m * TB + wv * 4 + bb]);
            }
#pragma unroll
            for (int bb = 0; bb < 4; ++bb)
                out[(size_t)(base + wv * 4 + bb) * (NJ * 65) + n * 65 + 64] = a64[bb] + b64v;
        }
    }
}

// ---------------- main fused kernel -------------------------------------------
__global__ __launch_bounds__(256, 2) void gnn_mfma(
    const float* __restrict__ x, const unsigned short* __restrict__ wp,
    const float* __restrict__ aw0, const float* __restrict__ b0,
    const float* __restrict__ aw1, const float* __restrict__ b1,
    const float* __restrict__ aw2, const float* __restrict__ b2,
    const float* __restrict__ aw3, const float* __restrict__ b3,
    float* __restrict__ out)
{
    __shared__ __align__(16) unsigned short buf[NJ * TB * 64];  // 49,152 B
    __shared__ __align__(8)  unsigned short abuf[NJ * TB];      //    768 B (L3 feat64)

    const int t = threadIdx.x;
    const int lane = t & 63;
    const int wv = t >> 6;
    const int base = blockIdx.x * TB;

    // wave-resident edge coefficients for all 4 layers (8 VGPRs, 8 gathers)
    const int e0 = EDGE_IDX[lane];
    const int e1 = EDGE_IDX[lane < 6 ? 64 + lane : 64];
    const unsigned int eA0 = __float_as_uint(aw0[e0]), eB0 = __float_as_uint(aw0[e1]);
    const unsigned int eA1 = __float_as_uint(aw1[e0]), eB1 = __float_as_uint(aw1[e1]);
    const unsigned int eA2 = __float_as_uint(aw2[e0]), eB2 = __float_as_uint(aw2[e1]);
    const unsigned int eA3 = __float_as_uint(aw3[e0]), eB3 = __float_as_uint(aw3[e1]);

    // load x tile -> swizzled [joint][b][feat] bf16, feats 13..31 zeroed (K=32
    // pad), joint 0 masked to zero (mask_root).
    for (int i = t; i < NJ * TB * 16; i += 256) {
        const int k = i >> 8;            // /(16 pairs * 16 b)
        const int b = (i >> 4) & 15;
        const int f2 = (i & 15) * 2;
        float v0 = 0.f, v1 = 0.f;
        if (k > 0) {
            const float* xr = x + (size_t)(base + b) * 312 + k * 13;
            if (f2 < 13)     v0 = xr[f2];
            if (f2 + 1 < 13) v1 = xr[f2 + 1];
        }
        const int row = k * TB + b;
        *(unsigned int*)&buf[row * 64 + (f2 ^ ((row & 7) << 3))] = pack2(v0, v1);
    }
    __syncthreads();

    linear_phase<1, 4>(buf, abuf, wp, wv, lane);                 // L0: K=32(13+pad)
    __syncthreads();
    agg_phase<false>(buf, abuf, eA0, eB0, nullptr, b0, nullptr, base, wv, lane);
    __syncthreads();
    linear_phase<2, 4>(buf, abuf, wp + 96 * 512, wv, lane);      // L1
    __syncthreads();
    agg_phase<false>(buf, abuf, eA1, eB1, nullptr, b1, nullptr, base, wv, lane);
    __syncthreads();
    linear_phase<2, 4>(buf, abuf, wp + 288 * 512, wv, lane);     // L2
    __syncthreads();
    agg_phase<false>(buf, abuf, eA2, eB2, nullptr, b2, nullptr, base, wv, lane);
    __syncthreads();
    linear_phase<2, 5>(buf, abuf, wp + 480 * 512, wv, lane);     // L3: MT=5 (65 cols)
    __syncthreads();
    agg_phase<true>(buf, abuf, eA3, eB3, aw3, b3, out, base, wv, lane);
}

extern "C" void kernel_launch(void* const* d_in, const int* in_sizes, int n_in,
                              void* d_out, int out_size, void* d_ws, size_t ws_size,
                              hipStream_t stream)
{
    const float* x   = (const float*)d_in[0];
    const float* w0  = (const float*)d_in[1];
    const float* aw0 = (const float*)d_in[2];
    const float* b0  = (const float*)d_in[3];
    const float* w1  = (const float*)d_in[4];
    const float* aw1 = (const float*)d_in[5];
    const float* b1  = (const float*)d_in[6];
    const float* w2  = (const float*)d_in[7];
    const float* aw2 = (const float*)d_in[8];
    const float* b2  = (const float*)d_in[9];
    const float* w3  = (const float*)d_in[10];
    const float* aw3 = (const float*)d_in[11];
    const float* b3  = (const float*)d_in[12];
    float* out = (float*)d_out;
    unsigned short* wp = (unsigned short*)d_ws;   // needs 737,280 B (720 frags * 1 KB)

    prepack<<<720, 256, 0, stream>>>(w0, w1, w2, w3, wp);

    const int blocks = 65536 / TB;   // 4096
    gnn_mfma<<<blocks, 256, 0, stream>>>(x, wp, aw0, b0, aw1, b1,
                                         aw2, b2, aw3, b3, out);
}